// Round 1
// baseline (1142.876 us; speedup 1.0000x reference)
//
#include <hip/hip_runtime.h>

#define A_N 65536
#define B_N 16
#define O_N 24
#define SELCAP 2048
#define KEEP 512

__device__ __forceinline__ float sl1(float d){
  float ad = fabsf(d);
  return ad < 1.0f ? 0.5f * d * d : ad - 0.5f;
}

__device__ __forceinline__ float iou_box(float ax1, float ay1, float ax2, float ay2,
                                         float bx1, float by1, float bx2, float by2){
  float tlx = fmaxf(ax1, bx1), tly = fmaxf(ay1, by1);
  float brx = fminf(ax2, bx2), bry = fminf(ay2, by2);
  float w = fmaxf(brx - tlx, 0.0f), h = fmaxf(bry - tly, 0.0f);
  float inter = w * h;
  float aa = (ax2 - ax1) * (ay2 - ay1);
  float ab = (bx2 - bx1) * (by2 - by1);
  return inter / (aa + ab - inter);
}

// ordering: value descending, index ascending (matches lax.top_k tie-break)
__device__ __forceinline__ bool before_kv(float va, int ia, float vb, int ib){
  return (va > vb) || (va == vb && ia < ib);
}

__device__ void bitonic_sort_2048(float* sv, int* si, int tid){
  for (int k = 2; k <= SELCAP; k <<= 1){
    for (int j = k >> 1; j > 0; j >>= 1){
      for (int t = tid; t < SELCAP; t += 256){
        int x = t ^ j;
        if (x > t){
          float va = sv[t], vb = sv[x];
          int ia = si[t], ib = si[x];
          bool up = ((t & k) == 0);
          bool sw = up ? before_kv(vb, ib, va, ia) : before_kv(va, ia, vb, ib);
          if (sw){ sv[t] = vb; si[t] = ib; sv[x] = va; si[x] = ia; }
        }
      }
      __syncthreads();
    }
  }
}

// One block per row r = ((b*24 + o)*2 + type); type 0 = prior-IoU, 1 = decoded-IoU.
// Exact top-512 of the row among positive-IoU anchors (sorted desc, idx asc),
// padded with (0.0, 0) if fewer than 512 positives exist.
__global__ __launch_bounds__(256) void sel_kernel(const float* __restrict__ loc,
    const float* __restrict__ priors, const float* __restrict__ targets,
    float* __restrict__ out_vals, int* __restrict__ out_idxs){
  __shared__ float sv[SELCAP];
  __shared__ int si[SELCAP];
  __shared__ int s_cnt;
  __shared__ float s_thr;
  const int r = blockIdx.x;
  const int type = r & 1;
  const int o = (r >> 1) % O_N;
  const int b = r / (O_N * 2);
  const int tid = threadIdx.x;
  const float* tg = targets + (size_t)(b * O_N + o) * 15;
  const float tx1 = tg[0], ty1 = tg[1], tx2 = tg[2], ty2 = tg[3];
  if (tid == 0){ s_cnt = 0; s_thr = 0.0f; }
  __syncthreads();
  for (int base = 0; base < A_N; base += 256){
    const int a = base + tid;
    const float4 pr = ((const float4*)priors)[a];
    float bx1, by1, bx2, by2;
    if (type == 0){
      bx1 = pr.x - pr.z * 0.5f; by1 = pr.y - pr.w * 0.5f;
      bx2 = pr.x + pr.z * 0.5f; by2 = pr.y + pr.w * 0.5f;
    } else {
      const float4 l = ((const float4*)loc)[(size_t)b * A_N + a];
      float cx = pr.x + l.x * 0.1f * pr.z;
      float cy = pr.y + l.y * 0.1f * pr.w;
      float w  = pr.z * expf(l.z * 0.2f);
      float h  = pr.w * expf(l.w * 0.2f);
      bx1 = cx - w * 0.5f; by1 = cy - h * 0.5f;
      bx2 = cx + w * 0.5f; by2 = cy + h * 0.5f;
    }
    const float v = iou_box(tx1, ty1, tx2, ty2, bx1, by1, bx2, by2);
    const float thr = s_thr;
    if ((v > thr) || (v == thr && thr > 0.0f)){
      int p = atomicAdd(&s_cnt, 1);
      sv[p] = v; si[p] = a;
    }
    __syncthreads();
    if (s_cnt > SELCAP - 256){
      int cnt = s_cnt;
      for (int jj = cnt + tid; jj < SELCAP; jj += 256){ sv[jj] = -1e30f; si[jj] = 0x7FFFFFFF; }
      __syncthreads();
      bitonic_sort_2048(sv, si, tid);
      if (tid == 0){ s_cnt = KEEP; s_thr = sv[KEEP - 1]; }
      __syncthreads();
    }
  }
  {
    int cnt = s_cnt;
    for (int jj = cnt + tid; jj < SELCAP; jj += 256){ sv[jj] = -1e30f; si[jj] = 0x7FFFFFFF; }
    __syncthreads();
    bitonic_sort_2048(sv, si, tid);
    int cnt2 = cnt < KEEP ? cnt : KEEP;
    for (int jj = tid; jj < KEEP; jj += 256){
      float v = (jj < cnt2) ? sv[jj] : 0.0f;
      int id  = (jj < cnt2) ? si[jj] : 0;
      out_vals[(size_t)r * KEEP + jj] = v;
      out_idxs[(size_t)r * KEEP + jj] = id;
    }
  }
}

// One wave per batch: replay the 24-step sequential match scan exactly.
__global__ __launch_bounds__(64) void scan_kernel(const float* __restrict__ vals,
    const int* __restrict__ idxs, int* __restrict__ p_idx, int* __restrict__ p_valid,
    unsigned int* __restrict__ bitset_g, int* __restrict__ n_pos_g){
  __shared__ unsigned int bs[A_N / 32];
  __shared__ float s_v[10];
  __shared__ int s_i[10];
  const int b = blockIdx.x;
  const int lane = threadIdx.x;
  for (int j = lane; j < A_N / 32; j += 64) bs[j] = 0u;
  __syncthreads();
  int npos = 0;
  const float PTH2 = (float)(0.35 + 0.05);
  for (int o = 0; o < O_N; ++o){
    for (int ph = 0; ph < 2; ++ph){
      const int r = (b * O_N + o) * 2 + ph;
      const float* rv = vals + (size_t)r * KEEP;
      const int* ri = idxs + (size_t)r * KEEP;
      int found = 0;
      for (int pos = 0; pos < KEEP && found < 10; pos += 64){
        float v = rv[pos + lane];
        int id = ri[pos + lane];
        bool unm = ((bs[id >> 5] >> (id & 31)) & 1u) == 0u;
        unsigned long long m = __ballot(unm);
        int rank = found + __popcll(m & ((1ull << lane) - 1ull));
        if (unm && rank < 10){ s_v[rank] = v; s_i[rank] = id; }
        int add = __popcll(m);
        found = (found + add > 10) ? 10 : (found + add);
        __syncthreads();
      }
      if (lane == 0){
        const float th = (ph == 0) ? 0.35f : PTH2;
        float fv[10]; int fi[10]; int vv[10];
        bool any = false;
        for (int j = 0; j < 10; ++j){
          fv[j] = (j < found) ? s_v[j] : 0.0f;
          fi[j] = (j < found) ? s_i[j] : 0;
          vv[j] = (fv[j] > th) ? 1 : 0;
          any = any || (vv[j] != 0);
        }
        if (ph == 0 && !any) vv[0] = 1;
        int base_slot = b * (O_N * 20) + o * 20 + ph * 10;
        for (int j = 0; j < 10; ++j){
          p_idx[base_slot + j] = fi[j];
          p_valid[base_slot + j] = vv[j];
          if (vv[j]){
            bs[fi[j] >> 5] |= (1u << (fi[j] & 31));
            npos++;
          }
        }
      }
      __syncthreads();
    }
  }
  for (int j = lane; j < A_N / 32; j += 64) bitset_g[b * (A_N / 32) + j] = bs[j];
  if (lane == 0) n_pos_g[b] = npos;
}

// Per (b,a): maxv over 24 truths (both IoU kinds), pos/neg classification,
// logsumexp, loss_pos accumulation, loss_c storage (-1 sentinel for non-neg).
__global__ __launch_bounds__(256) void anchor_kernel(const float* __restrict__ loc,
    const float* __restrict__ conf, const float* __restrict__ priors,
    const float* __restrict__ targets, const unsigned int* __restrict__ bitset_g,
    float* __restrict__ lossc, double* __restrict__ accum){
  const int b = blockIdx.y;
  const int a = blockIdx.x * 256 + threadIdx.x;
  __shared__ float tb[O_N * 4];
  __shared__ float red[256];
  if (threadIdx.x < O_N * 4){
    int o = threadIdx.x >> 2, k = threadIdx.x & 3;
    tb[threadIdx.x] = targets[(size_t)(b * O_N + o) * 15 + k];
  }
  __syncthreads();
  const float4 pr = ((const float4*)priors)[a];
  const float4 l = ((const float4*)loc)[(size_t)b * A_N + a];
  float pfx1 = pr.x - pr.z * 0.5f, pfy1 = pr.y - pr.w * 0.5f;
  float pfx2 = pr.x + pr.z * 0.5f, pfy2 = pr.y + pr.w * 0.5f;
  float cx = pr.x + l.x * 0.1f * pr.z;
  float cy = pr.y + l.y * 0.1f * pr.w;
  float w  = pr.z * expf(l.z * 0.2f);
  float h  = pr.w * expf(l.w * 0.2f);
  float dx1 = cx - w * 0.5f, dy1 = cy - h * 0.5f;
  float dx2 = cx + w * 0.5f, dy2 = cy + h * 0.5f;
  float maxv = 0.0f;
  for (int o = 0; o < O_N; ++o){
    float tx1 = tb[o * 4 + 0], ty1 = tb[o * 4 + 1], tx2 = tb[o * 4 + 2], ty2 = tb[o * 4 + 3];
    float va = iou_box(tx1, ty1, tx2, ty2, pfx1, pfy1, pfx2, pfy2);
    float vp = iou_box(tx1, ty1, tx2, ty2, dx1, dy1, dx2, dy2);
    maxv = fmaxf(maxv, fmaxf(va, vp));
  }
  bool masked = ((bitset_g[b * (A_N / 32) + (a >> 5)] >> (a & 31)) & 1u) != 0u;
  const float2 c = ((const float2*)conf)[(size_t)b * A_N + a];
  float mx = fmaxf(c.x, c.y);
  float lse = mx + log1pf(expf(-fabsf(c.x - c.y)));
  float lp = 0.0f;
  float lc = -1.0f;
  if (masked) lp = lse - c.y;
  else if (maxv < 0.4f) lc = lse - c.x;
  lossc[(size_t)b * A_N + a] = lc;
  red[threadIdx.x] = lp; __syncthreads();
  for (int s = 128; s > 0; s >>= 1){
    if (threadIdx.x < s) red[threadIdx.x] += red[threadIdx.x + s];
    __syncthreads();
  }
  if (threadIdx.x == 0 && red[0] != 0.0f) atomicAdd(&accum[2], (double)red[0]);
}

// Exact sum of top-(7*n_pos) loss_c among negatives per batch via 3-level radix
// select on float bits (monotonic for positive floats), then one sum pass.
__global__ __launch_bounds__(256) void mine_kernel(const float* __restrict__ lossc,
    const int* __restrict__ n_pos_g, double* __restrict__ accum){
  const int b = blockIdx.x;
  const int tid = threadIdx.x;
  __shared__ int hist[2048];
  __shared__ int s_bin, s_need, s_takeall;
  __shared__ unsigned s_cut;
  __shared__ int s_rat;
  __shared__ float red[256];
  const float* lc = lossc + (size_t)b * A_N;
  const int M = n_pos_g[b] * 7;
  if (M <= 0) return;
  for (int j = tid; j < 2048; j += 256) hist[j] = 0;
  __syncthreads();
  for (int a2 = tid; a2 < A_N; a2 += 256){
    float v = lc[a2];
    if (v >= 0.0f) atomicAdd(&hist[__float_as_uint(v) >> 21], 1);
  }
  __syncthreads();
  if (tid == 0){
    int cum = 0; s_takeall = 1;
    for (int bin = 2047; bin >= 0; --bin){
      int cc = hist[bin];
      if (cum + cc >= M){ s_bin = bin; s_need = M - cum; s_takeall = 0; break; }
      cum += cc;
    }
  }
  __syncthreads();
  unsigned cutbits = 0; int rat = 0;
  if (!s_takeall){
    unsigned t1 = (unsigned)s_bin;
    int need1 = s_need;
    __syncthreads();
    for (int j = tid; j < 2048; j += 256) hist[j] = 0;
    __syncthreads();
    for (int a2 = tid; a2 < A_N; a2 += 256){
      float v = lc[a2];
      if (v >= 0.0f){
        unsigned bits = __float_as_uint(v);
        if ((bits >> 21) == t1) atomicAdd(&hist[(bits >> 10) & 0x7FF], 1);
      }
    }
    __syncthreads();
    if (tid == 0){
      int cum = 0;
      for (int bin = 2047; bin >= 0; --bin){
        int cc = hist[bin];
        if (cum + cc >= need1){ s_bin = bin; s_need = need1 - cum; break; }
        cum += cc;
      }
    }
    __syncthreads();
    unsigned t2 = (unsigned)s_bin;
    int need2 = s_need;
    __syncthreads();
    for (int j = tid; j < 1024; j += 256) hist[j] = 0;
    __syncthreads();
    unsigned pre = (t1 << 11) | t2;
    for (int a2 = tid; a2 < A_N; a2 += 256){
      float v = lc[a2];
      if (v >= 0.0f){
        unsigned bits = __float_as_uint(v);
        if ((bits >> 10) == pre) atomicAdd(&hist[bits & 0x3FF], 1);
      }
    }
    __syncthreads();
    if (tid == 0){
      int cum = 0;
      for (int bin = 1023; bin >= 0; --bin){
        int cc = hist[bin];
        if (cum + cc >= need2){ s_cut = (pre << 10) | (unsigned)bin; s_rat = need2 - cum; break; }
        cum += cc;
      }
    }
    __syncthreads();
    cutbits = s_cut; rat = s_rat;
  }
  float sum = 0.0f;
  for (int a2 = tid; a2 < A_N; a2 += 256){
    float v = lc[a2];
    if (v >= 0.0f && __float_as_uint(v) > cutbits) sum += v;
  }
  red[tid] = sum; __syncthreads();
  for (int s = 128; s > 0; s >>= 1){
    if (tid < s) red[tid] += red[tid + s];
    __syncthreads();
  }
  if (tid == 0){
    double tot = (double)red[0] + (double)rat * (double)__uint_as_float(cutbits);
    atomicAdd(&accum[3], tot);
  }
}

// 480 selection slots per batch: loc + landmark regression losses and counts.
__global__ __launch_bounds__(512) void loss_lm_kernel(const float* __restrict__ loc,
    const float* __restrict__ landm, const float* __restrict__ priors,
    const float* __restrict__ targets, const int* __restrict__ p_idx,
    const int* __restrict__ p_valid, double* __restrict__ accum, int* __restrict__ cnts){
  const int b = blockIdx.x;
  const int j = threadIdx.x;
  float ll = 0.0f, lmv = 0.0f;
  int nv = 0, nv1 = 0;
  if (j < 480){
    int valid = p_valid[b * 480 + j];
    if (valid){
      int pid = p_idx[b * 480 + j];
      int t = j / 20;
      const float* tg = targets + (size_t)(b * O_N + t) * 15;
      float4 pr = ((const float4*)priors)[pid];
      float4 lp = ((const float4*)loc)[(size_t)b * A_N + pid];
      float gcx = ((tg[0] + tg[2]) * 0.5f - pr.x) / (0.1f * pr.z);
      float gcy = ((tg[1] + tg[3]) * 0.5f - pr.y) / (0.1f * pr.w);
      float gw = logf((tg[2] - tg[0]) / pr.z) / 0.2f;
      float gh = logf((tg[3] - tg[1]) / pr.w) / 0.2f;
      ll = sl1(lp.x - gcx) + sl1(lp.y - gcy) + sl1(lp.z - gw) + sl1(lp.w - gh);
      nv = 1;
      if (tg[14] == 1.0f){
        nv1 = 1;
        const float* lmp = landm + ((size_t)b * A_N + pid) * 6;
        for (int k = 0; k < 3; ++k){
          float gx = (tg[4 + 2 * k] - pr.x) / (0.1f * pr.z);
          float gy = (tg[5 + 2 * k] - pr.y) / (0.1f * pr.w);
          lmv += sl1(lmp[2 * k] - gx) + sl1(lmp[2 * k + 1] - gy);
        }
      }
    }
  }
  __shared__ float redf[512];
  __shared__ int redi[512];
  redf[j] = ll; __syncthreads();
  for (int s = 256; s > 0; s >>= 1){ if (j < s) redf[j] += redf[j + s]; __syncthreads(); }
  float llT = redf[0]; __syncthreads();
  redf[j] = lmv; __syncthreads();
  for (int s = 256; s > 0; s >>= 1){ if (j < s) redf[j] += redf[j + s]; __syncthreads(); }
  float lmT = redf[0]; __syncthreads();
  redi[j] = nv; __syncthreads();
  for (int s = 256; s > 0; s >>= 1){ if (j < s) redi[j] += redi[j + s]; __syncthreads(); }
  int nT = redi[0]; __syncthreads();
  redi[j] = nv1; __syncthreads();
  for (int s = 256; s > 0; s >>= 1){ if (j < s) redi[j] += redi[j + s]; __syncthreads(); }
  int n1T = redi[0];
  if (j == 0){
    atomicAdd(&accum[0], (double)llT);
    atomicAdd(&accum[1], (double)lmT);
    atomicAdd(&cnts[0], nT);
    atomicAdd(&cnts[1], n1T);
  }
}

__global__ void final_kernel(const double* __restrict__ accum,
                             const int* __restrict__ cnts, float* __restrict__ out){
  if (threadIdx.x == 0 && blockIdx.x == 0){
    double N = (double)cnts[0];
    double N1 = (double)cnts[1];
    out[0] = (float)(accum[0] / N);
    out[1] = (float)((accum[2] + accum[3]) / N);
    out[2] = (float)(accum[1] / N1);
  }
}

extern "C" void kernel_launch(void* const* d_in, const int* in_sizes, int n_in,
                              void* d_out, int out_size, void* d_ws, size_t ws_size,
                              hipStream_t stream){
  (void)in_sizes; (void)n_in; (void)out_size; (void)ws_size;
  const float* loc     = (const float*)d_in[0];
  const float* conf    = (const float*)d_in[1];
  const float* landm   = (const float*)d_in[2];
  const float* priors  = (const float*)d_in[3];
  const float* targets = (const float*)d_in[4];
  float* out = (float*)d_out;
  char* ws = (char*)d_ws;

  double* accum = (double*)ws;                 // [0]=loss_l [1]=loss_landm [2]=loss_pos [3]=loss_neg
  int* cnts = (int*)(ws + 32);                 // [0]=N [1]=N1
  size_t off = 64;
  float* vals = (float*)(ws + off); off += (size_t)B_N * O_N * 2 * KEEP * 4;
  int* idxs   = (int*)(ws + off);   off += (size_t)B_N * O_N * 2 * KEEP * 4;
  int* p_idx  = (int*)(ws + off);   off += (size_t)B_N * 480 * 4;
  int* p_val  = (int*)(ws + off);   off += (size_t)B_N * 480 * 4;
  unsigned int* bitset = (unsigned int*)(ws + off); off += (size_t)B_N * (A_N / 32) * 4;
  int* n_pos  = (int*)(ws + off);   off += 64;
  float* lossc = (float*)(ws + off); off += (size_t)B_N * A_N * 4;

  hipMemsetAsync(ws, 0, 64, stream);
  hipLaunchKernelGGL(sel_kernel, dim3(B_N * O_N * 2), dim3(256), 0, stream,
                     loc, priors, targets, vals, idxs);
  hipLaunchKernelGGL(scan_kernel, dim3(B_N), dim3(64), 0, stream,
                     vals, idxs, p_idx, p_val, bitset, n_pos);
  hipLaunchKernelGGL(anchor_kernel, dim3(A_N / 256, B_N), dim3(256), 0, stream,
                     loc, conf, priors, targets, bitset, lossc, accum);
  hipLaunchKernelGGL(mine_kernel, dim3(B_N), dim3(256), 0, stream,
                     lossc, n_pos, accum);
  hipLaunchKernelGGL(loss_lm_kernel, dim3(B_N), dim3(512), 0, stream,
                     loc, landm, priors, targets, p_idx, p_val, accum, cnts);
  hipLaunchKernelGGL(final_kernel, dim3(1), dim3(64), 0, stream, accum, cnts, out);
}

// Round 2
// 1104.746 us; speedup vs baseline: 1.0345x; 1.0345x over previous
//
#include <hip/hip_runtime.h>

#define A_N 65536
#define B_N 16
#define O_N 24
#define WBUF 1024
#define KEEP 512
#define NEG_INF (-1e30f)

__device__ __forceinline__ float sl1(float d){
  float ad = fabsf(d);
  return ad < 1.0f ? 0.5f * d * d : ad - 0.5f;
}

__device__ __forceinline__ float iou_box(float ax1, float ay1, float ax2, float ay2,
                                         float bx1, float by1, float bx2, float by2){
  float tlx = fmaxf(ax1, bx1), tly = fmaxf(ay1, by1);
  float brx = fminf(ax2, bx2), bry = fminf(ay2, by2);
  float w = fmaxf(brx - tlx, 0.0f), h = fmaxf(bry - tly, 0.0f);
  float inter = w * h;
  float aa = (ax2 - ax1) * (ay2 - ay1);
  float ab = (bx2 - bx1) * (by2 - by1);
  return inter / (aa + ab - inter);
}

// ordering: value descending, index ascending (matches lax.top_k tie-break)
__device__ __forceinline__ bool before_kv(float va, int ia, float vb, int ib){
  return (va > vb) || (va == vb && ia < ib);
}

// Decode all (b,a) boxes to point-form once; prior point-form; zero flags.
__global__ __launch_bounds__(256) void prep_kernel(const float* __restrict__ loc,
    const float* __restrict__ priors, float4* __restrict__ dec,
    float4* __restrict__ pf, unsigned char* __restrict__ flags){
  const int a = blockIdx.x * 256 + threadIdx.x;
  const int b = blockIdx.y;
  const float4 pr = ((const float4*)priors)[a];
  const float4 l = ((const float4*)loc)[(size_t)b * A_N + a];
  float cx = pr.x + l.x * 0.1f * pr.z;
  float cy = pr.y + l.y * 0.1f * pr.w;
  float w  = pr.z * expf(l.z * 0.2f);
  float h  = pr.w * expf(l.w * 0.2f);
  float4 d;
  d.x = cx - w * 0.5f; d.y = cy - h * 0.5f;
  d.z = cx + w * 0.5f; d.w = cy + h * 0.5f;
  dec[(size_t)b * A_N + a] = d;
  if (b == 0){
    float4 p;
    p.x = pr.x - pr.z * 0.5f; p.y = pr.y - pr.w * 0.5f;
    p.z = pr.x + pr.z * 0.5f; p.w = pr.y + pr.w * 0.5f;
    pf[a] = p;
  }
  flags[(size_t)b * A_N + a] = 0;
}

// Wave-synchronous bitonic sort of 1024 (desc by value, asc by index). No block barriers.
__device__ __forceinline__ void wave_sort_1024(float* sv, int* si, int base, int lane){
  for (int k = 2; k <= WBUF; k <<= 1){
    for (int j = k >> 1; j > 0; j >>= 1){
      #pragma unroll
      for (int s = 0; s < WBUF / 64; ++s){
        int t = lane + s * 64;
        int x = t ^ j;
        if (x > t){
          float va = sv[base + t], vb = sv[base + x];
          int ia = si[base + t], ib = si[base + x];
          bool up = ((t & k) == 0);
          bool sw = up ? before_kv(vb, ib, va, ia) : before_kv(va, ia, vb, ib);
          if (sw){ sv[base + t] = vb; si[base + t] = ib; sv[base + x] = va; si[base + x] = ia; }
        }
      }
      __builtin_amdgcn_wave_barrier();
    }
  }
}

// One block per row r = ((b*24 + o)*2 + type). Exact top-512 (desc, idx-asc) of the
// row among positive-IoU anchors, padded with (0,0). Wave-private buffers: no atomics,
// no block barriers in the streaming loop.
__global__ __launch_bounds__(256) void sel_kernel(const float4* __restrict__ dec,
    const float4* __restrict__ pf, const float* __restrict__ targets,
    unsigned char* __restrict__ flags,
    float* __restrict__ out_vals, int* __restrict__ out_idxs){
  __shared__ float sv[4 * WBUF];
  __shared__ int   si[4 * WBUF];
  __shared__ float mv[2048];
  __shared__ int   mi[2048];
  const int r = blockIdx.x;
  const int type = r & 1;
  const int o = (r >> 1) % O_N;
  const int b = r / (O_N * 2);
  const int tid = threadIdx.x;
  const int w = tid >> 6;
  const int lane = tid & 63;
  const int wbase = w * WBUF;
  const float* tg = targets + (size_t)(b * O_N + o) * 15;
  const float tx1 = tg[0], ty1 = tg[1], tx2 = tg[2], ty2 = tg[3];
  const unsigned long long lmask = (1ull << lane) - 1ull;
  const float4* src = (type == 0) ? pf : (dec + (size_t)b * A_N);
  unsigned char* fl = flags + (size_t)b * A_N;

  int cnt = 0;
  float thr = 0.0f;
  const int abase = w * (A_N / 4);
  for (int c = 0; c < (A_N / 4) / 64; ++c){
    const int a = abase + c * 64 + lane;
    const float4 bb = src[a];
    const float v = iou_box(tx1, ty1, tx2, ty2, bb.x, bb.y, bb.z, bb.w);
    if (v >= 0.4f) fl[a] = 1;
    bool acc = v > thr;
    unsigned long long m = __ballot(acc);
    if (acc){
      int p = cnt + (int)__popcll(m & lmask);
      sv[wbase + p] = v; si[wbase + p] = a;
    }
    cnt += (int)__popcll(m);
    if (cnt > WBUF - 64){
      for (int s2 = cnt + lane; s2 < WBUF; s2 += 64){ sv[wbase + s2] = NEG_INF; si[wbase + s2] = 0x7FFFFFFF; }
      __builtin_amdgcn_wave_barrier();
      wave_sort_1024(sv, si, wbase, lane);
      cnt = KEEP;
      thr = sv[wbase + KEEP - 1];
    }
  }
  // final wave-local sort
  for (int s2 = cnt + lane; s2 < WBUF; s2 += 64){ sv[wbase + s2] = NEG_INF; si[wbase + s2] = 0x7FFFFFFF; }
  __builtin_amdgcn_wave_barrier();
  wave_sort_1024(sv, si, wbase, lane);
  // lay out four sorted 512-runs, alternating direction, then bitonic-merge 2048
  for (int s2 = lane; s2 < KEEP; s2 += 64){
    int srcI = (w & 1) ? (KEEP - 1 - s2) : s2;
    mv[w * KEEP + s2] = sv[wbase + srcI];
    mi[w * KEEP + s2] = si[wbase + srcI];
  }
  __syncthreads();
  for (int k = 1024; k <= 2048; k <<= 1){
    for (int j = k >> 1; j > 0; j >>= 1){
      for (int t = tid; t < 2048; t += 256){
        int x = t ^ j;
        if (x > t){
          float va = mv[t], vb = mv[x];
          int ia = mi[t], ib = mi[x];
          bool up = ((t & k) == 0);
          bool sw = up ? before_kv(vb, ib, va, ia) : before_kv(va, ia, vb, ib);
          if (sw){ mv[t] = vb; mi[t] = ib; mv[x] = va; mi[x] = ia; }
        }
      }
      __syncthreads();
    }
  }
  for (int jj = tid; jj < KEEP; jj += 256){
    float v = mv[jj];
    bool padp = (v <= NEG_INF);
    out_vals[(size_t)r * KEEP + jj] = padp ? 0.0f : v;
    out_idxs[(size_t)r * KEEP + jj] = padp ? 0 : mi[jj];
  }
}

// One wave per batch: replay the 24-step sequential match scan exactly.
__global__ __launch_bounds__(64) void scan_kernel(const float* __restrict__ vals,
    const int* __restrict__ idxs, int* __restrict__ p_idx, int* __restrict__ p_valid,
    unsigned int* __restrict__ bitset_g, int* __restrict__ n_pos_g){
  __shared__ unsigned int bs[A_N / 32];
  __shared__ float s_v[10];
  __shared__ int s_i[10];
  const int b = blockIdx.x;
  const int lane = threadIdx.x;
  for (int j = lane; j < A_N / 32; j += 64) bs[j] = 0u;
  __syncthreads();
  int npos = 0;
  const float PTH2 = (float)(0.35 + 0.05);
  for (int o = 0; o < O_N; ++o){
    for (int ph = 0; ph < 2; ++ph){
      const int r = (b * O_N + o) * 2 + ph;
      const float* rv = vals + (size_t)r * KEEP;
      const int* ri = idxs + (size_t)r * KEEP;
      int found = 0;
      for (int pos = 0; pos < KEEP && found < 10; pos += 64){
        float v = rv[pos + lane];
        int id = ri[pos + lane];
        bool unm = ((bs[id >> 5] >> (id & 31)) & 1u) == 0u;
        unsigned long long m = __ballot(unm);
        int rank = found + __popcll(m & ((1ull << lane) - 1ull));
        if (unm && rank < 10){ s_v[rank] = v; s_i[rank] = id; }
        int add = __popcll(m);
        found = (found + add > 10) ? 10 : (found + add);
        __syncthreads();
      }
      if (lane == 0){
        const float th = (ph == 0) ? 0.35f : PTH2;
        float fv[10]; int fi[10]; int vv[10];
        bool any = false;
        for (int j = 0; j < 10; ++j){
          fv[j] = (j < found) ? s_v[j] : 0.0f;
          fi[j] = (j < found) ? s_i[j] : 0;
          vv[j] = (fv[j] > th) ? 1 : 0;
          any = any || (vv[j] != 0);
        }
        if (ph == 0 && !any) vv[0] = 1;
        int base_slot = b * (O_N * 20) + o * 20 + ph * 10;
        for (int j = 0; j < 10; ++j){
          p_idx[base_slot + j] = fi[j];
          p_valid[base_slot + j] = vv[j];
          if (vv[j]){
            bs[fi[j] >> 5] |= (1u << (fi[j] & 31));
            npos++;
          }
        }
      }
      __syncthreads();
    }
  }
  for (int j = lane; j < A_N / 32; j += 64) bitset_g[b * (A_N / 32) + j] = bs[j];
  if (lane == 0) n_pos_g[b] = npos;
}

// Per (b,a): pos/neg classification from flags+bitset, logsumexp, loss_pos, loss_c.
__global__ __launch_bounds__(256) void anchor_kernel(const float* __restrict__ conf,
    const unsigned char* __restrict__ flags, const unsigned int* __restrict__ bitset_g,
    float* __restrict__ lossc, double* __restrict__ accum){
  const int b = blockIdx.y;
  const int a = blockIdx.x * 256 + threadIdx.x;
  __shared__ float red[256];
  bool masked = ((bitset_g[b * (A_N / 32) + (a >> 5)] >> (a & 31)) & 1u) != 0u;
  const float2 c = ((const float2*)conf)[(size_t)b * A_N + a];
  float mx = fmaxf(c.x, c.y);
  float lse = mx + log1pf(expf(-fabsf(c.x - c.y)));
  float lp = 0.0f;
  float lc = -1.0f;
  if (masked) lp = lse - c.y;
  else if (!flags[(size_t)b * A_N + a]) lc = lse - c.x;
  lossc[(size_t)b * A_N + a] = lc;
  red[threadIdx.x] = lp; __syncthreads();
  for (int s = 128; s > 0; s >>= 1){
    if (threadIdx.x < s) red[threadIdx.x] += red[threadIdx.x + s];
    __syncthreads();
  }
  if (threadIdx.x == 0 && red[0] != 0.0f) atomicAdd(&accum[2], (double)red[0]);
}

// Exact sum of top-(7*n_pos) loss_c among negatives per batch via 3-level radix
// select on float bits, then one sum pass. 512 threads, float4 sweeps.
__global__ __launch_bounds__(512) void mine_kernel(const float* __restrict__ lossc,
    const int* __restrict__ n_pos_g, double* __restrict__ accum){
  const int b = blockIdx.x;
  const int tid = threadIdx.x;
  __shared__ int hist[2048];
  __shared__ int s_bin, s_need, s_takeall;
  __shared__ unsigned s_cut;
  __shared__ int s_rat;
  __shared__ float red[512];
  const float4* lc4 = (const float4*)(lossc + (size_t)b * A_N);
  const int M = n_pos_g[b] * 7;
  if (M <= 0) return;
  for (int j = tid; j < 2048; j += 512) hist[j] = 0;
  __syncthreads();
  for (int q = tid; q < A_N / 4; q += 512){
    float4 v4 = lc4[q];
    if (v4.x >= 0.0f) atomicAdd(&hist[__float_as_uint(v4.x) >> 21], 1);
    if (v4.y >= 0.0f) atomicAdd(&hist[__float_as_uint(v4.y) >> 21], 1);
    if (v4.z >= 0.0f) atomicAdd(&hist[__float_as_uint(v4.z) >> 21], 1);
    if (v4.w >= 0.0f) atomicAdd(&hist[__float_as_uint(v4.w) >> 21], 1);
  }
  __syncthreads();
  if (tid == 0){
    int cum = 0; s_takeall = 1;
    for (int bin = 2047; bin >= 0; --bin){
      int cc = hist[bin];
      if (cum + cc >= M){ s_bin = bin; s_need = M - cum; s_takeall = 0; break; }
      cum += cc;
    }
  }
  __syncthreads();
  unsigned cutbits = 0; int rat = 0;
  if (!s_takeall){
    unsigned t1 = (unsigned)s_bin;
    int need1 = s_need;
    __syncthreads();
    for (int j = tid; j < 2048; j += 512) hist[j] = 0;
    __syncthreads();
    for (int q = tid; q < A_N / 4; q += 512){
      float4 v4 = lc4[q];
      float vv[4] = {v4.x, v4.y, v4.z, v4.w};
      #pragma unroll
      for (int e = 0; e < 4; ++e){
        if (vv[e] >= 0.0f){
          unsigned bits = __float_as_uint(vv[e]);
          if ((bits >> 21) == t1) atomicAdd(&hist[(bits >> 10) & 0x7FF], 1);
        }
      }
    }
    __syncthreads();
    if (tid == 0){
      int cum = 0;
      for (int bin = 2047; bin >= 0; --bin){
        int cc = hist[bin];
        if (cum + cc >= need1){ s_bin = bin; s_need = need1 - cum; break; }
        cum += cc;
      }
    }
    __syncthreads();
    unsigned t2 = (unsigned)s_bin;
    int need2 = s_need;
    __syncthreads();
    for (int j = tid; j < 1024; j += 512) hist[j] = 0;
    __syncthreads();
    unsigned pre = (t1 << 11) | t2;
    for (int q = tid; q < A_N / 4; q += 512){
      float4 v4 = lc4[q];
      float vv[4] = {v4.x, v4.y, v4.z, v4.w};
      #pragma unroll
      for (int e = 0; e < 4; ++e){
        if (vv[e] >= 0.0f){
          unsigned bits = __float_as_uint(vv[e]);
          if ((bits >> 10) == pre) atomicAdd(&hist[bits & 0x3FF], 1);
        }
      }
    }
    __syncthreads();
    if (tid == 0){
      int cum = 0;
      for (int bin = 1023; bin >= 0; --bin){
        int cc = hist[bin];
        if (cum + cc >= need2){ s_cut = (pre << 10) | (unsigned)bin; s_rat = need2 - cum; break; }
        cum += cc;
      }
    }
    __syncthreads();
    cutbits = s_cut; rat = s_rat;
  }
  float sum = 0.0f;
  for (int q = tid; q < A_N / 4; q += 512){
    float4 v4 = lc4[q];
    float vv[4] = {v4.x, v4.y, v4.z, v4.w};
    #pragma unroll
    for (int e = 0; e < 4; ++e){
      if (vv[e] >= 0.0f && __float_as_uint(vv[e]) > cutbits) sum += vv[e];
    }
  }
  red[tid] = sum; __syncthreads();
  for (int s = 256; s > 0; s >>= 1){
    if (tid < s) red[tid] += red[tid + s];
    __syncthreads();
  }
  if (tid == 0){
    double tot = (double)red[0] + (double)rat * (double)__uint_as_float(cutbits);
    atomicAdd(&accum[3], tot);
  }
}

// 480 selection slots per batch: loc + landmark regression losses and counts.
__global__ __launch_bounds__(512) void loss_lm_kernel(const float* __restrict__ loc,
    const float* __restrict__ landm, const float* __restrict__ priors,
    const float* __restrict__ targets, const int* __restrict__ p_idx,
    const int* __restrict__ p_valid, double* __restrict__ accum, int* __restrict__ cnts){
  const int b = blockIdx.x;
  const int j = threadIdx.x;
  float ll = 0.0f, lmv = 0.0f;
  int nv = 0, nv1 = 0;
  if (j < 480){
    int valid = p_valid[b * 480 + j];
    if (valid){
      int pid = p_idx[b * 480 + j];
      int t = j / 20;
      const float* tg = targets + (size_t)(b * O_N + t) * 15;
      float4 pr = ((const float4*)priors)[pid];
      float4 lp = ((const float4*)loc)[(size_t)b * A_N + pid];
      float gcx = ((tg[0] + tg[2]) * 0.5f - pr.x) / (0.1f * pr.z);
      float gcy = ((tg[1] + tg[3]) * 0.5f - pr.y) / (0.1f * pr.w);
      float gw = logf((tg[2] - tg[0]) / pr.z) / 0.2f;
      float gh = logf((tg[3] - tg[1]) / pr.w) / 0.2f;
      ll = sl1(lp.x - gcx) + sl1(lp.y - gcy) + sl1(lp.z - gw) + sl1(lp.w - gh);
      nv = 1;
      if (tg[14] == 1.0f){
        nv1 = 1;
        const float* lmp = landm + ((size_t)b * A_N + pid) * 6;
        for (int k = 0; k < 3; ++k){
          float gx = (tg[4 + 2 * k] - pr.x) / (0.1f * pr.z);
          float gy = (tg[5 + 2 * k] - pr.y) / (0.1f * pr.w);
          lmv += sl1(lmp[2 * k] - gx) + sl1(lmp[2 * k + 1] - gy);
        }
      }
    }
  }
  __shared__ float redf[512];
  __shared__ int redi[512];
  redf[j] = ll; __syncthreads();
  for (int s = 256; s > 0; s >>= 1){ if (j < s) redf[j] += redf[j + s]; __syncthreads(); }
  float llT = redf[0]; __syncthreads();
  redf[j] = lmv; __syncthreads();
  for (int s = 256; s > 0; s >>= 1){ if (j < s) redf[j] += redf[j + s]; __syncthreads(); }
  float lmT = redf[0]; __syncthreads();
  redi[j] = nv; __syncthreads();
  for (int s = 256; s > 0; s >>= 1){ if (j < s) redi[j] += redi[j + s]; __syncthreads(); }
  int nT = redi[0]; __syncthreads();
  redi[j] = nv1; __syncthreads();
  for (int s = 256; s > 0; s >>= 1){ if (j < s) redi[j] += redi[j + s]; __syncthreads(); }
  int n1T = redi[0];
  if (j == 0){
    atomicAdd(&accum[0], (double)llT);
    atomicAdd(&accum[1], (double)lmT);
    atomicAdd(&cnts[0], nT);
    atomicAdd(&cnts[1], n1T);
  }
}

__global__ void final_kernel(const double* __restrict__ accum,
                             const int* __restrict__ cnts, float* __restrict__ out){
  if (threadIdx.x == 0 && blockIdx.x == 0){
    double N = (double)cnts[0];
    double N1 = (double)cnts[1];
    out[0] = (float)(accum[0] / N);
    out[1] = (float)((accum[2] + accum[3]) / N);
    out[2] = (float)(accum[1] / N1);
  }
}

extern "C" void kernel_launch(void* const* d_in, const int* in_sizes, int n_in,
                              void* d_out, int out_size, void* d_ws, size_t ws_size,
                              hipStream_t stream){
  (void)in_sizes; (void)n_in; (void)out_size; (void)ws_size;
  const float* loc     = (const float*)d_in[0];
  const float* conf    = (const float*)d_in[1];
  const float* landm   = (const float*)d_in[2];
  const float* priors  = (const float*)d_in[3];
  const float* targets = (const float*)d_in[4];
  float* out = (float*)d_out;
  char* ws = (char*)d_ws;

  double* accum = (double*)ws;                 // [0]=loss_l [1]=loss_landm [2]=loss_pos [3]=loss_neg
  int* cnts = (int*)(ws + 32);                 // [0]=N [1]=N1
  size_t off = 64;
  float4* dec = (float4*)(ws + off);  off += (size_t)B_N * A_N * 16;
  float4* pf  = (float4*)(ws + off);  off += (size_t)A_N * 16;
  unsigned char* flags = (unsigned char*)(ws + off); off += (size_t)B_N * A_N;
  float* vals = (float*)(ws + off); off += (size_t)B_N * O_N * 2 * KEEP * 4;
  int* idxs   = (int*)(ws + off);   off += (size_t)B_N * O_N * 2 * KEEP * 4;
  int* p_idx  = (int*)(ws + off);   off += (size_t)B_N * 480 * 4;
  int* p_val  = (int*)(ws + off);   off += (size_t)B_N * 480 * 4;
  unsigned int* bitset = (unsigned int*)(ws + off); off += (size_t)B_N * (A_N / 32) * 4;
  int* n_pos  = (int*)(ws + off);   off += 64;
  float* lossc = (float*)(ws + off); off += (size_t)B_N * A_N * 4;

  hipMemsetAsync(ws, 0, 64, stream);
  hipLaunchKernelGGL(prep_kernel, dim3(A_N / 256, B_N), dim3(256), 0, stream,
                     loc, priors, dec, pf, flags);
  hipLaunchKernelGGL(sel_kernel, dim3(B_N * O_N * 2), dim3(256), 0, stream,
                     dec, pf, targets, flags, vals, idxs);
  hipLaunchKernelGGL(scan_kernel, dim3(B_N), dim3(64), 0, stream,
                     vals, idxs, p_idx, p_val, bitset, n_pos);
  hipLaunchKernelGGL(anchor_kernel, dim3(A_N / 256, B_N), dim3(256), 0, stream,
                     conf, flags, bitset, lossc, accum);
  hipLaunchKernelGGL(mine_kernel, dim3(B_N), dim3(512), 0, stream,
                     lossc, n_pos, accum);
  hipLaunchKernelGGL(loss_lm_kernel, dim3(B_N), dim3(512), 0, stream,
                     loc, landm, priors, targets, p_idx, p_val, accum, cnts);
  hipLaunchKernelGGL(final_kernel, dim3(1), dim3(64), 0, stream, accum, cnts, out);
}

// Round 3
// 714.344 us; speedup vs baseline: 1.5999x; 1.5465x over previous
//
#include <hip/hip_runtime.h>

#define A_N 65536
#define B_N 16
#define O_N 24
#define WBUF 1024
#define KEEP 512
#define PF 4

typedef unsigned long long u64;

__device__ __forceinline__ float sl1(float d){
  float ad = fabsf(d);
  return ad < 1.0f ? 0.5f * d * d : ad - 0.5f;
}

__device__ __forceinline__ float iou_box(float ax1, float ay1, float ax2, float ay2,
                                         float bx1, float by1, float bx2, float by2){
  float tlx = fmaxf(ax1, bx1), tly = fmaxf(ay1, by1);
  float brx = fminf(ax2, bx2), bry = fminf(ay2, by2);
  float w = fmaxf(brx - tlx, 0.0f), h = fmaxf(bry - tly, 0.0f);
  float inter = w * h;
  float aa = (ax2 - ax1) * (ay2 - ay1);
  float ab = (bx2 - bx1) * (by2 - by1);
  return inter / (aa + ab - inter);
}

// Decode all (b,a) boxes to point-form once; prior point-form; zero flags.
__global__ __launch_bounds__(256) void prep_kernel(const float* __restrict__ loc,
    const float* __restrict__ priors, float4* __restrict__ dec,
    float4* __restrict__ pf, unsigned char* __restrict__ flags){
  const int a = blockIdx.x * 256 + threadIdx.x;
  const int b = blockIdx.y;
  const float4 pr = ((const float4*)priors)[a];
  const float4 l = ((const float4*)loc)[(size_t)b * A_N + a];
  float cx = pr.x + l.x * 0.1f * pr.z;
  float cy = pr.y + l.y * 0.1f * pr.w;
  float w  = pr.z * expf(l.z * 0.2f);
  float h  = pr.w * expf(l.w * 0.2f);
  float4 d;
  d.x = cx - w * 0.5f; d.y = cy - h * 0.5f;
  d.z = cx + w * 0.5f; d.w = cy + h * 0.5f;
  dec[(size_t)b * A_N + a] = d;
  if (b == 0){
    float4 p;
    p.x = pr.x - pr.z * 0.5f; p.y = pr.y - pr.w * 0.5f;
    p.z = pr.x + pr.z * 0.5f; p.w = pr.y + pr.w * 0.5f;
    pf[a] = p;
  }
  flags[(size_t)b * A_N + a] = 0;
}

// Wave-synchronous descending bitonic sort of 1024 u64 keys. No block barriers.
__device__ __forceinline__ void wave_sort_u64(u64* sk, int base, int lane){
  for (int k = 2; k <= WBUF; k <<= 1){
    for (int j = k >> 1; j > 0; j >>= 1){
      #pragma unroll
      for (int s = 0; s < WBUF / 64; ++s){
        int t = lane + s * 64;
        int x = t ^ j;
        if (x > t){
          u64 ka = sk[base + t], kb = sk[base + x];
          bool up = ((t & k) == 0);
          bool sw = up ? (kb > ka) : (ka > kb);
          if (sw){ sk[base + t] = kb; sk[base + x] = ka; }
        }
      }
      __builtin_amdgcn_wave_barrier();
    }
  }
}

// One block per row r = ((b*24 + o)*2 + type). Exact top-512 (value desc, idx asc)
// among positive-IoU anchors; padded with (0,0). Key = (vbits<<32)|~a so a single
// descending u64 sort gives the required ordering.
__global__ __launch_bounds__(256) void sel_kernel(const float4* __restrict__ dec,
    const float4* __restrict__ pf, const float* __restrict__ targets,
    unsigned char* __restrict__ flags,
    float* __restrict__ out_vals, int* __restrict__ out_idxs){
  __shared__ u64 sk[4 * WBUF];
  const int r = blockIdx.x;
  const int type = r & 1;
  const int o = (r >> 1) % O_N;
  const int b = r / (O_N * 2);
  const int tid = threadIdx.x;
  const int w = tid >> 6;
  const int lane = tid & 63;
  const int wbase = w * WBUF;
  const float* tg = targets + (size_t)(b * O_N + o) * 15;
  const float tx1 = tg[0], ty1 = tg[1], tx2 = tg[2], ty2 = tg[3];
  const u64 lmask = (1ull << lane) - 1ull;
  const float4* src = (type == 0) ? pf : (dec + (size_t)b * A_N);
  unsigned char* fl = flags + (size_t)b * A_N;

  int cnt = 0;
  float thr = 0.0f;
  const int abase = w * (A_N / 4);   // 16384 anchors per wave
  const int NCH = (A_N / 4) / 64;    // 256 chunks of 64
  float4 nxt[PF];
  #pragma unroll
  for (int u = 0; u < PF; ++u) nxt[u] = src[abase + u * 64 + lane];
  for (int c = 0; c < NCH; c += PF){
    float4 cur[PF];
    #pragma unroll
    for (int u = 0; u < PF; ++u) cur[u] = nxt[u];
    if (c + PF < NCH){
      #pragma unroll
      for (int u = 0; u < PF; ++u) nxt[u] = src[abase + (c + PF + u) * 64 + lane];
    }
    #pragma unroll
    for (int u = 0; u < PF; ++u){
      const int a = abase + (c + u) * 64 + lane;
      const float4 bb = cur[u];
      const float v = iou_box(tx1, ty1, tx2, ty2, bb.x, bb.y, bb.z, bb.w);
      if (v >= 0.4f) fl[a] = 1;
      bool acc = v > thr;
      u64 m = __ballot(acc);
      if (acc){
        int p = cnt + (int)__popcll(m & lmask);
        sk[wbase + p] = ((u64)__float_as_uint(v) << 32) | (u64)(~(unsigned)a);
      }
      cnt += (int)__popcll(m);
    }
    if (cnt > WBUF - PF * 64){
      for (int s2 = cnt + lane; s2 < WBUF; s2 += 64) sk[wbase + s2] = 0ull;
      __builtin_amdgcn_wave_barrier();
      wave_sort_u64(sk, wbase, lane);
      cnt = KEEP;
      thr = __uint_as_float((unsigned)(sk[wbase + KEEP - 1] >> 32));
    }
  }
  // final wave-local sort
  for (int s2 = cnt + lane; s2 < WBUF; s2 += 64) sk[wbase + s2] = 0ull;
  __builtin_amdgcn_wave_barrier();
  wave_sort_u64(sk, wbase, lane);
  // reverse odd waves' top-512 run (alternating directions for bitonic merge)
  if (w & 1){
    for (int s2 = lane; s2 < KEEP / 2; s2 += 64){
      u64 a0 = sk[wbase + s2], a1 = sk[wbase + KEEP - 1 - s2];
      sk[wbase + s2] = a1; sk[wbase + KEEP - 1 - s2] = a0;
    }
    __builtin_amdgcn_wave_barrier();
  }
  __syncthreads();
  // block bitonic merge of the four 512-runs over virtual index m(t)=((t>>9)<<10)|(t&511)
  for (int k = 1024; k <= 2048; k <<= 1){
    for (int j = k >> 1; j > 0; j >>= 1){
      for (int t = tid; t < 2048; t += 256){
        int x = t ^ j;
        if (x > t){
          int mt = ((t >> 9) << 10) | (t & 511);
          int mx = ((x >> 9) << 10) | (x & 511);
          u64 ka = sk[mt], kb = sk[mx];
          bool up = ((t & k) == 0);
          bool sw = up ? (kb > ka) : (ka > kb);
          if (sw){ sk[mt] = kb; sk[mx] = ka; }
        }
      }
      __syncthreads();
    }
  }
  for (int jj = tid; jj < KEEP; jj += 256){
    u64 kk = sk[jj];  // m(jj)==jj for jj<512
    out_vals[(size_t)r * KEEP + jj] = __uint_as_float((unsigned)(kk >> 32));
    out_idxs[(size_t)r * KEEP + jj] = (kk == 0ull) ? 0 : (int)(~(unsigned)kk);
  }
}

// One wave per batch: replay the 24-step sequential match scan exactly.
__global__ __launch_bounds__(64) void scan_kernel(const float* __restrict__ vals,
    const int* __restrict__ idxs, int* __restrict__ p_idx, int* __restrict__ p_valid,
    unsigned int* __restrict__ bitset_g, int* __restrict__ n_pos_g){
  __shared__ unsigned int bs[A_N / 32];
  __shared__ float s_v[10];
  __shared__ int s_i[10];
  const int b = blockIdx.x;
  const int lane = threadIdx.x;
  for (int j = lane; j < A_N / 32; j += 64) bs[j] = 0u;
  __syncthreads();
  int npos = 0;
  const float PTH2 = (float)(0.35 + 0.05);
  for (int o = 0; o < O_N; ++o){
    for (int ph = 0; ph < 2; ++ph){
      const int r = (b * O_N + o) * 2 + ph;
      const float* rv = vals + (size_t)r * KEEP;
      const int* ri = idxs + (size_t)r * KEEP;
      int found = 0;
      for (int pos = 0; pos < KEEP && found < 10; pos += 64){
        float v = rv[pos + lane];
        int id = ri[pos + lane];
        bool unm = ((bs[id >> 5] >> (id & 31)) & 1u) == 0u;
        unsigned long long m = __ballot(unm);
        int rank = found + __popcll(m & ((1ull << lane) - 1ull));
        if (unm && rank < 10){ s_v[rank] = v; s_i[rank] = id; }
        int add = __popcll(m);
        found = (found + add > 10) ? 10 : (found + add);
        __syncthreads();
      }
      if (lane == 0){
        const float th = (ph == 0) ? 0.35f : PTH2;
        float fv[10]; int fi[10]; int vv[10];
        bool any = false;
        for (int j = 0; j < 10; ++j){
          fv[j] = (j < found) ? s_v[j] : 0.0f;
          fi[j] = (j < found) ? s_i[j] : 0;
          vv[j] = (fv[j] > th) ? 1 : 0;
          any = any || (vv[j] != 0);
        }
        if (ph == 0 && !any) vv[0] = 1;
        int base_slot = b * (O_N * 20) + o * 20 + ph * 10;
        for (int j = 0; j < 10; ++j){
          p_idx[base_slot + j] = fi[j];
          p_valid[base_slot + j] = vv[j];
          if (vv[j]){
            bs[fi[j] >> 5] |= (1u << (fi[j] & 31));
            npos++;
          }
        }
      }
      __syncthreads();
    }
  }
  for (int j = lane; j < A_N / 32; j += 64) bitset_g[b * (A_N / 32) + j] = bs[j];
  if (lane == 0) n_pos_g[b] = npos;
}

// Per (b,a): pos/neg classification, logsumexp, per-block partial of loss_pos, loss_c.
__global__ __launch_bounds__(256) void anchor_kernel(const float* __restrict__ conf,
    const unsigned char* __restrict__ flags, const unsigned int* __restrict__ bitset_g,
    float* __restrict__ lossc, float* __restrict__ partial){
  const int b = blockIdx.y;
  const int a = blockIdx.x * 256 + threadIdx.x;
  __shared__ float red[256];
  bool masked = ((bitset_g[b * (A_N / 32) + (a >> 5)] >> (a & 31)) & 1u) != 0u;
  const float2 c = ((const float2*)conf)[(size_t)b * A_N + a];
  float mx = fmaxf(c.x, c.y);
  float lse = mx + log1pf(expf(-fabsf(c.x - c.y)));
  float lp = 0.0f;
  float lc = -1.0f;
  if (masked) lp = lse - c.y;
  else if (!flags[(size_t)b * A_N + a]) lc = lse - c.x;
  lossc[(size_t)b * A_N + a] = lc;
  red[threadIdx.x] = lp; __syncthreads();
  for (int s = 128; s > 0; s >>= 1){
    if (threadIdx.x < s) red[threadIdx.x] += red[threadIdx.x + s];
    __syncthreads();
  }
  if (threadIdx.x == 0) partial[blockIdx.y * gridDim.x + blockIdx.x] = red[0];
}

// Exact sum of top-(7*n_pos) loss_c among negatives per batch via 3-level radix
// select; group-sums parallelize the top-down bin search.
__global__ __launch_bounds__(512) void mine_kernel(const float* __restrict__ lossc,
    const int* __restrict__ n_pos_g, double* __restrict__ accum){
  const int b = blockIdx.x;
  const int tid = threadIdx.x;
  __shared__ int hist[2048];
  __shared__ int gsum[256];
  __shared__ int s_bin, s_need, s_takeall;
  __shared__ unsigned s_cut;
  __shared__ int s_rat;
  __shared__ float red[512];
  const float4* lc4 = (const float4*)(lossc + (size_t)b * A_N);
  const int M = n_pos_g[b] * 7;
  if (M <= 0) return;
  // ---- level 1: bits >> 21 ----
  for (int j = tid; j < 2048; j += 512) hist[j] = 0;
  __syncthreads();
  for (int q = tid; q < A_N / 4; q += 512){
    float4 v4 = lc4[q];
    if (v4.x >= 0.0f) atomicAdd(&hist[__float_as_uint(v4.x) >> 21], 1);
    if (v4.y >= 0.0f) atomicAdd(&hist[__float_as_uint(v4.y) >> 21], 1);
    if (v4.z >= 0.0f) atomicAdd(&hist[__float_as_uint(v4.z) >> 21], 1);
    if (v4.w >= 0.0f) atomicAdd(&hist[__float_as_uint(v4.w) >> 21], 1);
  }
  __syncthreads();
  if (tid < 256){
    int s = 0;
    #pragma unroll
    for (int e = 0; e < 8; ++e) s += hist[tid * 8 + e];
    gsum[tid] = s;
  }
  __syncthreads();
  if (tid == 0){
    int cum = 0; s_takeall = 1;
    for (int g = 255; g >= 0; --g){
      int gc = gsum[g];
      if (cum + gc >= M){
        for (int bin = g * 8 + 7; bin >= g * 8; --bin){
          int cc = hist[bin];
          if (cum + cc >= M){ s_bin = bin; s_need = M - cum; s_takeall = 0; break; }
          cum += cc;
        }
        break;
      }
      cum += gc;
    }
  }
  __syncthreads();
  unsigned cutbits = 0; int rat = 0;
  if (!s_takeall){
    unsigned t1 = (unsigned)s_bin;
    int need1 = s_need;
    __syncthreads();
    // ---- level 2: bits >> 10, within t1 ----
    for (int j = tid; j < 2048; j += 512) hist[j] = 0;
    __syncthreads();
    for (int q = tid; q < A_N / 4; q += 512){
      float4 v4 = lc4[q];
      float vv[4] = {v4.x, v4.y, v4.z, v4.w};
      #pragma unroll
      for (int e = 0; e < 4; ++e){
        if (vv[e] >= 0.0f){
          unsigned bits = __float_as_uint(vv[e]);
          if ((bits >> 21) == t1) atomicAdd(&hist[(bits >> 10) & 0x7FF], 1);
        }
      }
    }
    __syncthreads();
    if (tid < 256){
      int s = 0;
      #pragma unroll
      for (int e = 0; e < 8; ++e) s += hist[tid * 8 + e];
      gsum[tid] = s;
    }
    __syncthreads();
    if (tid == 0){
      int cum = 0;
      for (int g = 255; g >= 0; --g){
        int gc = gsum[g];
        if (cum + gc >= need1){
          for (int bin = g * 8 + 7; bin >= g * 8; --bin){
            int cc = hist[bin];
            if (cum + cc >= need1){ s_bin = bin; s_need = need1 - cum; break; }
            cum += cc;
          }
          break;
        }
        cum += gc;
      }
    }
    __syncthreads();
    unsigned t2 = (unsigned)s_bin;
    int need2 = s_need;
    __syncthreads();
    // ---- level 3: low 10 bits, within (t1,t2) ----
    for (int j = tid; j < 1024; j += 512) hist[j] = 0;
    __syncthreads();
    unsigned pre = (t1 << 11) | t2;
    for (int q = tid; q < A_N / 4; q += 512){
      float4 v4 = lc4[q];
      float vv[4] = {v4.x, v4.y, v4.z, v4.w};
      #pragma unroll
      for (int e = 0; e < 4; ++e){
        if (vv[e] >= 0.0f){
          unsigned bits = __float_as_uint(vv[e]);
          if ((bits >> 10) == pre) atomicAdd(&hist[bits & 0x3FF], 1);
        }
      }
    }
    __syncthreads();
    if (tid < 256){
      int s = 0;
      #pragma unroll
      for (int e = 0; e < 4; ++e) s += hist[tid * 4 + e];
      gsum[tid] = s;
    }
    __syncthreads();
    if (tid == 0){
      int cum = 0;
      for (int g = 255; g >= 0; --g){
        int gc = gsum[g];
        if (cum + gc >= need2){
          for (int bin = g * 4 + 3; bin >= g * 4; --bin){
            int cc = hist[bin];
            if (cum + cc >= need2){ s_cut = (pre << 10) | (unsigned)bin; s_rat = need2 - cum; break; }
            cum += cc;
          }
          break;
        }
        cum += gc;
      }
    }
    __syncthreads();
    cutbits = s_cut; rat = s_rat;
  }
  float sum = 0.0f;
  for (int q = tid; q < A_N / 4; q += 512){
    float4 v4 = lc4[q];
    float vv[4] = {v4.x, v4.y, v4.z, v4.w};
    #pragma unroll
    for (int e = 0; e < 4; ++e){
      if (vv[e] >= 0.0f && __float_as_uint(vv[e]) > cutbits) sum += vv[e];
    }
  }
  red[tid] = sum; __syncthreads();
  for (int s = 256; s > 0; s >>= 1){
    if (tid < s) red[tid] += red[tid + s];
    __syncthreads();
  }
  if (tid == 0){
    double tot = (double)red[0] + (double)rat * (double)__uint_as_float(cutbits);
    atomicAdd(&accum[3], tot);
  }
}

// 480 selection slots per batch: loc + landmark regression losses and counts.
__global__ __launch_bounds__(512) void loss_lm_kernel(const float* __restrict__ loc,
    const float* __restrict__ landm, const float* __restrict__ priors,
    const float* __restrict__ targets, const int* __restrict__ p_idx,
    const int* __restrict__ p_valid, double* __restrict__ accum, int* __restrict__ cnts){
  const int b = blockIdx.x;
  const int j = threadIdx.x;
  float ll = 0.0f, lmv = 0.0f;
  int nv = 0, nv1 = 0;
  if (j < 480){
    int valid = p_valid[b * 480 + j];
    if (valid){
      int pid = p_idx[b * 480 + j];
      int t = j / 20;
      const float* tg = targets + (size_t)(b * O_N + t) * 15;
      float4 pr = ((const float4*)priors)[pid];
      float4 lp = ((const float4*)loc)[(size_t)b * A_N + pid];
      float gcx = ((tg[0] + tg[2]) * 0.5f - pr.x) / (0.1f * pr.z);
      float gcy = ((tg[1] + tg[3]) * 0.5f - pr.y) / (0.1f * pr.w);
      float gw = logf((tg[2] - tg[0]) / pr.z) / 0.2f;
      float gh = logf((tg[3] - tg[1]) / pr.w) / 0.2f;
      ll = sl1(lp.x - gcx) + sl1(lp.y - gcy) + sl1(lp.z - gw) + sl1(lp.w - gh);
      nv = 1;
      if (tg[14] == 1.0f){
        nv1 = 1;
        const float* lmp = landm + ((size_t)b * A_N + pid) * 6;
        for (int k = 0; k < 3; ++k){
          float gx = (tg[4 + 2 * k] - pr.x) / (0.1f * pr.z);
          float gy = (tg[5 + 2 * k] - pr.y) / (0.1f * pr.w);
          lmv += sl1(lmp[2 * k] - gx) + sl1(lmp[2 * k + 1] - gy);
        }
      }
    }
  }
  __shared__ float redf[512];
  __shared__ int redi[512];
  redf[j] = ll; __syncthreads();
  for (int s = 256; s > 0; s >>= 1){ if (j < s) redf[j] += redf[j + s]; __syncthreads(); }
  float llT = redf[0]; __syncthreads();
  redf[j] = lmv; __syncthreads();
  for (int s = 256; s > 0; s >>= 1){ if (j < s) redf[j] += redf[j + s]; __syncthreads(); }
  float lmT = redf[0]; __syncthreads();
  redi[j] = nv; __syncthreads();
  for (int s = 256; s > 0; s >>= 1){ if (j < s) redi[j] += redi[j + s]; __syncthreads(); }
  int nT = redi[0]; __syncthreads();
  redi[j] = nv1; __syncthreads();
  for (int s = 256; s > 0; s >>= 1){ if (j < s) redi[j] += redi[j + s]; __syncthreads(); }
  int n1T = redi[0];
  if (j == 0){
    atomicAdd(&accum[0], (double)llT);
    atomicAdd(&accum[1], (double)lmT);
    atomicAdd(&cnts[0], nT);
    atomicAdd(&cnts[1], n1T);
  }
}

__global__ __launch_bounds__(256) void final_kernel(const double* __restrict__ accum,
    const int* __restrict__ cnts, const float* __restrict__ partial, int npart,
    float* __restrict__ out){
  __shared__ double red[256];
  double s = 0.0;
  for (int i = threadIdx.x; i < npart; i += 256) s += (double)partial[i];
  red[threadIdx.x] = s; __syncthreads();
  for (int st = 128; st > 0; st >>= 1){
    if (threadIdx.x < st) red[threadIdx.x] += red[threadIdx.x + st];
    __syncthreads();
  }
  if (threadIdx.x == 0){
    double N = (double)cnts[0];
    double N1 = (double)cnts[1];
    out[0] = (float)(accum[0] / N);
    out[1] = (float)((red[0] + accum[3]) / N);
    out[2] = (float)(accum[1] / N1);
  }
}

extern "C" void kernel_launch(void* const* d_in, const int* in_sizes, int n_in,
                              void* d_out, int out_size, void* d_ws, size_t ws_size,
                              hipStream_t stream){
  (void)in_sizes; (void)n_in; (void)out_size; (void)ws_size;
  const float* loc     = (const float*)d_in[0];
  const float* conf    = (const float*)d_in[1];
  const float* landm   = (const float*)d_in[2];
  const float* priors  = (const float*)d_in[3];
  const float* targets = (const float*)d_in[4];
  float* out = (float*)d_out;
  char* ws = (char*)d_ws;

  double* accum = (double*)ws;                 // [0]=loss_l [1]=loss_landm [3]=loss_neg
  int* cnts = (int*)(ws + 32);                 // [0]=N [1]=N1
  size_t off = 64;
  float4* dec = (float4*)(ws + off);  off += (size_t)B_N * A_N * 16;
  float4* pf  = (float4*)(ws + off);  off += (size_t)A_N * 16;
  unsigned char* flags = (unsigned char*)(ws + off); off += (size_t)B_N * A_N;
  float* vals = (float*)(ws + off); off += (size_t)B_N * O_N * 2 * KEEP * 4;
  int* idxs   = (int*)(ws + off);   off += (size_t)B_N * O_N * 2 * KEEP * 4;
  int* p_idx  = (int*)(ws + off);   off += (size_t)B_N * 480 * 4;
  int* p_val  = (int*)(ws + off);   off += (size_t)B_N * 480 * 4;
  unsigned int* bitset = (unsigned int*)(ws + off); off += (size_t)B_N * (A_N / 32) * 4;
  int* n_pos  = (int*)(ws + off);   off += 64;
  float* lossc = (float*)(ws + off); off += (size_t)B_N * A_N * 4;
  float* partial = (float*)(ws + off); off += (size_t)B_N * (A_N / 256) * 4;

  hipMemsetAsync(ws, 0, 64, stream);
  hipLaunchKernelGGL(prep_kernel, dim3(A_N / 256, B_N), dim3(256), 0, stream,
                     loc, priors, dec, pf, flags);
  hipLaunchKernelGGL(sel_kernel, dim3(B_N * O_N * 2), dim3(256), 0, stream,
                     dec, pf, targets, flags, vals, idxs);
  hipLaunchKernelGGL(scan_kernel, dim3(B_N), dim3(64), 0, stream,
                     vals, idxs, p_idx, p_val, bitset, n_pos);
  hipLaunchKernelGGL(anchor_kernel, dim3(A_N / 256, B_N), dim3(256), 0, stream,
                     conf, flags, bitset, lossc, partial);
  hipLaunchKernelGGL(mine_kernel, dim3(B_N), dim3(512), 0, stream,
                     lossc, n_pos, accum);
  hipLaunchKernelGGL(loss_lm_kernel, dim3(B_N), dim3(512), 0, stream,
                     loc, landm, priors, targets, p_idx, p_val, accum, cnts);
  hipLaunchKernelGGL(final_kernel, dim3(1), dim3(256), 0, stream,
                     accum, cnts, partial, B_N * (A_N / 256), out);
}

// Round 4
// 457.408 us; speedup vs baseline: 2.4986x; 1.5617x over previous
//
#include <hip/hip_runtime.h>

#define A_N 65536
#define B_N 16
#define O_N 24
#define KEEP 512
#define SELCAP 2048
#define PF 4

typedef unsigned long long u64;

__device__ __forceinline__ float sl1(float d){
  float ad = fabsf(d);
  return ad < 1.0f ? 0.5f * d * d : ad - 0.5f;
}

__device__ __forceinline__ float iou_box(float ax1, float ay1, float ax2, float ay2,
                                         float bx1, float by1, float bx2, float by2){
  float tlx = fmaxf(ax1, bx1), tly = fmaxf(ay1, by1);
  float brx = fminf(ax2, bx2), bry = fminf(ay2, by2);
  float w = fmaxf(brx - tlx, 0.0f), h = fmaxf(bry - tly, 0.0f);
  float inter = w * h;
  float aa = (ax2 - ax1) * (ay2 - ay1);
  float ab = (bx2 - bx1) * (by2 - by1);
  return inter / (aa + ab - inter);
}

// Decode all (b,a) boxes to point-form once; prior point-form; zero flags.
__global__ __launch_bounds__(256) void prep_kernel(const float* __restrict__ loc,
    const float* __restrict__ priors, float4* __restrict__ dec,
    float4* __restrict__ pf, unsigned char* __restrict__ flags){
  const int a = blockIdx.x * 256 + threadIdx.x;
  const int b = blockIdx.y;
  const float4 pr = ((const float4*)priors)[a];
  const float4 l = ((const float4*)loc)[(size_t)b * A_N + a];
  float cx = pr.x + l.x * 0.1f * pr.z;
  float cy = pr.y + l.y * 0.1f * pr.w;
  float w  = pr.z * expf(l.z * 0.2f);
  float h  = pr.w * expf(l.w * 0.2f);
  float4 d;
  d.x = cx - w * 0.5f; d.y = cy - h * 0.5f;
  d.z = cx + w * 0.5f; d.w = cy + h * 0.5f;
  dec[(size_t)b * A_N + a] = d;
  if (b == 0){
    float4 p;
    p.x = pr.x - pr.z * 0.5f; p.y = pr.y - pr.w * 0.5f;
    p.z = pr.x + pr.z * 0.5f; p.w = pr.y + pr.w * 0.5f;
    pf[a] = p;
  }
  flags[(size_t)b * A_N + a] = 0;
}

// Wave-synchronous bitonic sort of 512 u64 keys; asc=false -> descending.
__device__ __forceinline__ void wave_sort_512(u64* sk, int base, int lane, bool asc){
  for (int k = 2; k <= 512; k <<= 1){
    for (int j = k >> 1; j > 0; j >>= 1){
      #pragma unroll
      for (int s = 0; s < 8; ++s){
        int t = lane + s * 64;
        int x = t ^ j;
        if (x > t){
          u64 ka = sk[base + t], kb = sk[base + x];
          bool up = (((t & k) == 0) != asc);
          bool sw = up ? (kb > ka) : (ka > kb);
          if (sw){ sk[base + t] = kb; sk[base + x] = ka; }
        }
      }
      __builtin_amdgcn_wave_barrier();
    }
  }
}

// One block per row r = ((b*24 + o)*2 + type). Exact top-512 (value desc, idx asc)
// among positive-IoU anchors via 2-pass radix select + single sort.
// Key = (vbits<<32)|~a so descending u64 order == (value desc, idx asc).
__global__ __launch_bounds__(256) void sel_kernel(const float4* __restrict__ dec,
    const float4* __restrict__ pf, const float* __restrict__ targets,
    unsigned char* __restrict__ flags,
    float* __restrict__ out_vals, int* __restrict__ out_idxs){
  __shared__ unsigned hist[2048];
  __shared__ u64 sk[SELCAP];
  __shared__ unsigned gsum_s[64];
  __shared__ int s_b1, s_cnt;
  const int r = blockIdx.x;
  const int type = r & 1;
  const int o = (r >> 1) % O_N;
  const int b = r / (O_N * 2);
  const int tid = threadIdx.x;
  const int w = tid >> 6;
  const int lane = tid & 63;
  const u64 lmask = (1ull << lane) - 1ull;
  const float* tg = targets + (size_t)(b * O_N + o) * 15;
  const float tx1 = tg[0], ty1 = tg[1], tx2 = tg[2], ty2 = tg[3];
  const float4* src = (type == 0) ? pf : (dec + (size_t)b * A_N);
  unsigned char* fl = flags + (size_t)b * A_N;

  for (int j = tid; j < 2048; j += 256) hist[j] = 0u;
  if (tid == 0) s_cnt = 0;
  __syncthreads();

  const int NCH = A_N / 256;  // 256 chunks of 256 anchors
  // ---- pass A: histogram of positive IoU bits>>19, plus flags ----
  {
    float4 nxt[PF];
    #pragma unroll
    for (int u = 0; u < PF; ++u) nxt[u] = src[u * 256 + tid];
    for (int c = 0; c < NCH; c += PF){
      float4 cur[PF];
      #pragma unroll
      for (int u = 0; u < PF; ++u) cur[u] = nxt[u];
      if (c + PF < NCH){
        #pragma unroll
        for (int u = 0; u < PF; ++u) nxt[u] = src[(c + PF + u) * 256 + tid];
      }
      #pragma unroll
      for (int u = 0; u < PF; ++u){
        const int a = (c + u) * 256 + tid;
        const float4 bb = cur[u];
        const float v = iou_box(tx1, ty1, tx2, ty2, bb.x, bb.y, bb.z, bb.w);
        if (v >= 0.4f) fl[a] = 1;
        if (v > 0.0f){
          unsigned bin = __float_as_uint(v) >> 19;
          if (bin > 2047u) bin = 2047u;
          atomicAdd(&hist[bin], 1u);
        }
      }
    }
  }
  __syncthreads();
  // ---- find boundary bin b1 (bin of the 512th-largest), or 0 if < 512 positives ----
  if (tid < 64){
    unsigned s = 0;
    #pragma unroll
    for (int e = 0; e < 32; ++e) s += hist[tid * 32 + e];
    gsum_s[tid] = s;
  }
  __syncthreads();
  if (tid == 0){
    int cum = 0, b1 = -1;
    for (int g = 63; g >= 0 && b1 < 0; --g){
      unsigned gs = gsum_s[g];
      if (cum + (int)gs >= KEEP){
        for (int bin = g * 32 + 31; bin >= g * 32; --bin){
          cum += (int)hist[bin];
          if (cum >= KEEP){ b1 = bin; break; }
        }
      } else cum += (int)gs;
    }
    s_b1 = (b1 < 0) ? 0 : b1;
  }
  __syncthreads();
  const int b1 = s_b1;
  // ---- pass B: compact candidates with bin >= b1 ----
  {
    float4 nxt[PF];
    #pragma unroll
    for (int u = 0; u < PF; ++u) nxt[u] = src[u * 256 + tid];
    for (int c = 0; c < NCH; c += PF){
      float4 cur[PF];
      #pragma unroll
      for (int u = 0; u < PF; ++u) cur[u] = nxt[u];
      if (c + PF < NCH){
        #pragma unroll
        for (int u = 0; u < PF; ++u) nxt[u] = src[(c + PF + u) * 256 + tid];
      }
      #pragma unroll
      for (int u = 0; u < PF; ++u){
        const int a = (c + u) * 256 + tid;
        const float4 bb = cur[u];
        const float v = iou_box(tx1, ty1, tx2, ty2, bb.x, bb.y, bb.z, bb.w);
        unsigned bits = __float_as_uint(v);
        unsigned bin = bits >> 19;
        if (bin > 2047u) bin = 2047u;
        bool acc = (v > 0.0f) && ((int)bin >= b1);
        u64 m = __ballot(acc);
        if (m){
          int base = 0;
          if (lane == 0) base = atomicAdd(&s_cnt, (int)__popcll(m));
          base = __shfl(base, 0);
          if (acc){
            int p = base + (int)__popcll(m & lmask);
            if (p < SELCAP) sk[p] = ((u64)bits << 32) | (u64)(~(unsigned)a);
          }
        }
      }
    }
  }
  __syncthreads();
  int cnt = s_cnt; if (cnt > SELCAP) cnt = SELCAP;
  for (int j = cnt + tid; j < SELCAP; j += 256) sk[j] = 0ull;
  __syncthreads();
  // ---- sort: per-wave 512 (alternating direction) + 21-stage block merge ----
  wave_sort_512(sk, w * 512, lane, (w & 1) != 0);
  __syncthreads();
  for (int k = 1024; k <= 2048; k <<= 1){
    for (int j = k >> 1; j > 0; j >>= 1){
      for (int t = tid; t < SELCAP; t += 256){
        int x = t ^ j;
        if (x > t){
          u64 ka = sk[t], kb = sk[x];
          bool up = ((t & k) == 0);
          bool sw = up ? (kb > ka) : (ka > kb);
          if (sw){ sk[t] = kb; sk[x] = ka; }
        }
      }
      __syncthreads();
    }
  }
  for (int jj = tid; jj < KEEP; jj += 256){
    u64 kk = sk[jj];
    out_vals[(size_t)r * KEEP + jj] = __uint_as_float((unsigned)(kk >> 32));
    out_idxs[(size_t)r * KEEP + jj] = (kk == 0ull) ? 0 : (int)(~(unsigned)kk);
  }
}

// One wave per batch: replay the 24-step sequential match scan exactly.
// Chunk-0 of all 48 rows preloaded into LDS (common case needs only those).
__global__ __launch_bounds__(64) void scan_kernel(const float* __restrict__ vals,
    const int* __restrict__ idxs, int* __restrict__ p_idx, int* __restrict__ p_valid,
    unsigned int* __restrict__ bitset_g, int* __restrict__ n_pos_g){
  __shared__ unsigned int bs[A_N / 32];
  __shared__ float pv0[48][64];
  __shared__ int pi0[48][64];
  __shared__ float s_v[10];
  __shared__ int s_i[10];
  const int b = blockIdx.x;
  const int lane = threadIdx.x;
  for (int j = lane; j < A_N / 32; j += 64) bs[j] = 0u;
  for (int row = 0; row < 48; ++row){
    pv0[row][lane] = vals[(size_t)(b * 48 + row) * KEEP + lane];
    pi0[row][lane] = idxs[(size_t)(b * 48 + row) * KEEP + lane];
  }
  __syncthreads();
  int npos = 0;
  const float PTH2 = (float)(0.35 + 0.05);
  for (int o = 0; o < O_N; ++o){
    for (int ph = 0; ph < 2; ++ph){
      const int row48 = o * 2 + ph;
      const int r = b * 48 + row48;
      const float* rv = vals + (size_t)r * KEEP;
      const int* ri = idxs + (size_t)r * KEEP;
      int found = 0;
      for (int pos = 0; pos < KEEP && found < 10; pos += 64){
        float v; int id;
        if (pos == 0){ v = pv0[row48][lane]; id = pi0[row48][lane]; }
        else { v = rv[pos + lane]; id = ri[pos + lane]; }
        bool unm = ((bs[id >> 5] >> (id & 31)) & 1u) == 0u;
        unsigned long long m = __ballot(unm);
        int rank = found + __popcll(m & ((1ull << lane) - 1ull));
        if (unm && rank < 10){ s_v[rank] = v; s_i[rank] = id; }
        int add = __popcll(m);
        found = (found + add > 10) ? 10 : (found + add);
        __syncthreads();
      }
      if (lane == 0){
        const float th = (ph == 0) ? 0.35f : PTH2;
        float fv[10]; int fi[10]; int vv[10];
        bool any = false;
        for (int j = 0; j < 10; ++j){
          fv[j] = (j < found) ? s_v[j] : 0.0f;
          fi[j] = (j < found) ? s_i[j] : 0;
          vv[j] = (fv[j] > th) ? 1 : 0;
          any = any || (vv[j] != 0);
        }
        if (ph == 0 && !any) vv[0] = 1;
        int base_slot = b * (O_N * 20) + o * 20 + ph * 10;
        for (int j = 0; j < 10; ++j){
          p_idx[base_slot + j] = fi[j];
          p_valid[base_slot + j] = vv[j];
          if (vv[j]){
            bs[fi[j] >> 5] |= (1u << (fi[j] & 31));
            npos++;
          }
        }
      }
      __syncthreads();
    }
  }
  for (int j = lane; j < A_N / 32; j += 64) bitset_g[b * (A_N / 32) + j] = bs[j];
  if (lane == 0) n_pos_g[b] = npos;
}

// Per (b,a): pos/neg classification, logsumexp, per-block partial of loss_pos, loss_c.
__global__ __launch_bounds__(256) void anchor_kernel(const float* __restrict__ conf,
    const unsigned char* __restrict__ flags, const unsigned int* __restrict__ bitset_g,
    float* __restrict__ lossc, float* __restrict__ partial){
  const int b = blockIdx.y;
  const int a = blockIdx.x * 256 + threadIdx.x;
  __shared__ float red[256];
  bool masked = ((bitset_g[b * (A_N / 32) + (a >> 5)] >> (a & 31)) & 1u) != 0u;
  const float2 c = ((const float2*)conf)[(size_t)b * A_N + a];
  float mx = fmaxf(c.x, c.y);
  float lse = mx + log1pf(expf(-fabsf(c.x - c.y)));
  float lp = 0.0f;
  float lc = -1.0f;
  if (masked) lp = lse - c.y;
  else if (!flags[(size_t)b * A_N + a]) lc = lse - c.x;
  lossc[(size_t)b * A_N + a] = lc;
  red[threadIdx.x] = lp; __syncthreads();
  for (int s = 128; s > 0; s >>= 1){
    if (threadIdx.x < s) red[threadIdx.x] += red[threadIdx.x + s];
    __syncthreads();
  }
  if (threadIdx.x == 0) partial[blockIdx.y * gridDim.x + blockIdx.x] = red[0];
}

// Exact sum of top-(7*n_pos) loss_c among negatives per batch.
// Sweep 1: 8192-bin histogram (bits>>19). Sweep 2: sum of bins > b1 and compact
// boundary bin. Sort boundary, add its top-`need` (tie choice irrelevant to a sum).
__global__ __launch_bounds__(512) void mine_kernel(const float* __restrict__ lossc,
    const int* __restrict__ n_pos_g, double* __restrict__ accum){
  __shared__ unsigned hist[8192];
  __shared__ u64 sk[SELCAP];
  __shared__ unsigned gsum_s[256];
  __shared__ int s_b1, s_need, s_cnt;
  __shared__ float red[512];
  const int b = blockIdx.x;
  const int tid = threadIdx.x;
  const int w = tid >> 6;
  const int lane = tid & 63;
  const u64 lmask = (1ull << lane) - 1ull;
  const float4* lc4 = (const float4*)(lossc + (size_t)b * A_N);
  const int M = n_pos_g[b] * 7;
  if (M <= 0) return;
  for (int j = tid; j < 8192; j += 512) hist[j] = 0u;
  if (tid == 0) s_cnt = 0;
  __syncthreads();
  // ---- sweep 1: histogram ----
  for (int q = tid; q < A_N / 4; q += 512){
    float4 v4 = lc4[q];
    float vv[4] = {v4.x, v4.y, v4.z, v4.w};
    #pragma unroll
    for (int e = 0; e < 4; ++e){
      if (vv[e] >= 0.0f){
        unsigned bin = __float_as_uint(vv[e]) >> 19;
        if (bin > 8191u) bin = 8191u;
        atomicAdd(&hist[bin], 1u);
      }
    }
  }
  __syncthreads();
  if (tid < 256){
    unsigned s = 0;
    #pragma unroll
    for (int e = 0; e < 32; ++e) s += hist[tid * 32 + e];
    gsum_s[tid] = s;
  }
  __syncthreads();
  if (tid == 0){
    int cum = 0, b1 = -1, need = 0;
    for (int g = 255; g >= 0 && b1 < 0; --g){
      unsigned gs = gsum_s[g];
      if (cum + (int)gs >= M){
        for (int bin = g * 32 + 31; bin >= g * 32; --bin){
          int cc = (int)hist[bin];
          if (cum + cc >= M){ b1 = bin; need = M - cum; break; }
          cum += cc;
        }
      } else cum += (int)gs;
    }
    s_b1 = b1;       // -1 => take all negatives
    s_need = need;
  }
  __syncthreads();
  const int b1 = s_b1;
  const int need = s_need;
  // ---- sweep 2: sum above-boundary + compact boundary bin ----
  float sum = 0.0f;
  for (int q = tid; q < A_N / 4; q += 512){
    float4 v4 = lc4[q];
    float vv[4] = {v4.x, v4.y, v4.z, v4.w};
    #pragma unroll
    for (int e = 0; e < 4; ++e){
      float v = vv[e];
      bool isneg = (v >= 0.0f);
      unsigned bits = __float_as_uint(v);
      unsigned bin = bits >> 19;
      if (bin > 8191u) bin = 8191u;
      if (isneg && (int)bin > b1) sum += v;
      bool acc = isneg && ((int)bin == b1);
      u64 m = __ballot(acc);
      if (m){
        int base = 0;
        if (lane == 0) base = atomicAdd(&s_cnt, (int)__popcll(m));
        base = __shfl(base, 0);
        if (acc){
          int p = base + (int)__popcll(m & lmask);
          if (p < SELCAP) sk[p] = (u64)bits;
        }
      }
    }
  }
  __syncthreads();
  int cnt = s_cnt; if (cnt > SELCAP) cnt = SELCAP;
  for (int j = cnt + tid; j < SELCAP; j += 512) sk[j] = 0ull;
  __syncthreads();
  if (w < 4) wave_sort_512(sk, w * 512, lane, (w & 1) != 0);
  __syncthreads();
  for (int k = 1024; k <= 2048; k <<= 1){
    for (int j = k >> 1; j > 0; j >>= 1){
      for (int t = tid; t < SELCAP; t += 512){
        int x = t ^ j;
        if (x > t){
          u64 ka = sk[t], kb = sk[x];
          bool up = ((t & k) == 0);
          bool sw = up ? (kb > ka) : (ka > kb);
          if (sw){ sk[t] = kb; sk[x] = ka; }
        }
      }
      __syncthreads();
    }
  }
  for (int i = tid; i < need; i += 512) sum += __uint_as_float((unsigned)sk[i]);
  red[tid] = sum; __syncthreads();
  for (int s = 256; s > 0; s >>= 1){
    if (tid < s) red[tid] += red[tid + s];
    __syncthreads();
  }
  if (tid == 0) atomicAdd(&accum[3], (double)red[0]);
}

// 480 selection slots per batch: loc + landmark regression losses and counts.
__global__ __launch_bounds__(512) void loss_lm_kernel(const float* __restrict__ loc,
    const float* __restrict__ landm, const float* __restrict__ priors,
    const float* __restrict__ targets, const int* __restrict__ p_idx,
    const int* __restrict__ p_valid, double* __restrict__ accum, int* __restrict__ cnts){
  const int b = blockIdx.x;
  const int j = threadIdx.x;
  float ll = 0.0f, lmv = 0.0f;
  int nv = 0, nv1 = 0;
  if (j < 480){
    int valid = p_valid[b * 480 + j];
    if (valid){
      int pid = p_idx[b * 480 + j];
      int t = j / 20;
      const float* tg = targets + (size_t)(b * O_N + t) * 15;
      float4 pr = ((const float4*)priors)[pid];
      float4 lp = ((const float4*)loc)[(size_t)b * A_N + pid];
      float gcx = ((tg[0] + tg[2]) * 0.5f - pr.x) / (0.1f * pr.z);
      float gcy = ((tg[1] + tg[3]) * 0.5f - pr.y) / (0.1f * pr.w);
      float gw = logf((tg[2] - tg[0]) / pr.z) / 0.2f;
      float gh = logf((tg[3] - tg[1]) / pr.w) / 0.2f;
      ll = sl1(lp.x - gcx) + sl1(lp.y - gcy) + sl1(lp.z - gw) + sl1(lp.w - gh);
      nv = 1;
      if (tg[14] == 1.0f){
        nv1 = 1;
        const float* lmp = landm + ((size_t)b * A_N + pid) * 6;
        for (int k = 0; k < 3; ++k){
          float gx = (tg[4 + 2 * k] - pr.x) / (0.1f * pr.z);
          float gy = (tg[5 + 2 * k] - pr.y) / (0.1f * pr.w);
          lmv += sl1(lmp[2 * k] - gx) + sl1(lmp[2 * k + 1] - gy);
        }
      }
    }
  }
  __shared__ float redf[512];
  __shared__ int redi[512];
  redf[j] = ll; __syncthreads();
  for (int s = 256; s > 0; s >>= 1){ if (j < s) redf[j] += redf[j + s]; __syncthreads(); }
  float llT = redf[0]; __syncthreads();
  redf[j] = lmv; __syncthreads();
  for (int s = 256; s > 0; s >>= 1){ if (j < s) redf[j] += redf[j + s]; __syncthreads(); }
  float lmT = redf[0]; __syncthreads();
  redi[j] = nv; __syncthreads();
  for (int s = 256; s > 0; s >>= 1){ if (j < s) redi[j] += redi[j + s]; __syncthreads(); }
  int nT = redi[0]; __syncthreads();
  redi[j] = nv1; __syncthreads();
  for (int s = 256; s > 0; s >>= 1){ if (j < s) redi[j] += redi[j + s]; __syncthreads(); }
  int n1T = redi[0];
  if (j == 0){
    atomicAdd(&accum[0], (double)llT);
    atomicAdd(&accum[1], (double)lmT);
    atomicAdd(&cnts[0], nT);
    atomicAdd(&cnts[1], n1T);
  }
}

__global__ __launch_bounds__(256) void final_kernel(const double* __restrict__ accum,
    const int* __restrict__ cnts, const float* __restrict__ partial, int npart,
    float* __restrict__ out){
  __shared__ double red[256];
  double s = 0.0;
  for (int i = threadIdx.x; i < npart; i += 256) s += (double)partial[i];
  red[threadIdx.x] = s; __syncthreads();
  for (int st = 128; st > 0; st >>= 1){
    if (threadIdx.x < st) red[threadIdx.x] += red[threadIdx.x + st];
    __syncthreads();
  }
  if (threadIdx.x == 0){
    double N = (double)cnts[0];
    double N1 = (double)cnts[1];
    out[0] = (float)(accum[0] / N);
    out[1] = (float)((red[0] + accum[3]) / N);
    out[2] = (float)(accum[1] / N1);
  }
}

extern "C" void kernel_launch(void* const* d_in, const int* in_sizes, int n_in,
                              void* d_out, int out_size, void* d_ws, size_t ws_size,
                              hipStream_t stream){
  (void)in_sizes; (void)n_in; (void)out_size; (void)ws_size;
  const float* loc     = (const float*)d_in[0];
  const float* conf    = (const float*)d_in[1];
  const float* landm   = (const float*)d_in[2];
  const float* priors  = (const float*)d_in[3];
  const float* targets = (const float*)d_in[4];
  float* out = (float*)d_out;
  char* ws = (char*)d_ws;

  double* accum = (double*)ws;                 // [0]=loss_l [1]=loss_landm [3]=loss_neg
  int* cnts = (int*)(ws + 32);                 // [0]=N [1]=N1
  size_t off = 64;
  float4* dec = (float4*)(ws + off);  off += (size_t)B_N * A_N * 16;
  float4* pf  = (float4*)(ws + off);  off += (size_t)A_N * 16;
  unsigned char* flags = (unsigned char*)(ws + off); off += (size_t)B_N * A_N;
  float* vals = (float*)(ws + off); off += (size_t)B_N * O_N * 2 * KEEP * 4;
  int* idxs   = (int*)(ws + off);   off += (size_t)B_N * O_N * 2 * KEEP * 4;
  int* p_idx  = (int*)(ws + off);   off += (size_t)B_N * 480 * 4;
  int* p_val  = (int*)(ws + off);   off += (size_t)B_N * 480 * 4;
  unsigned int* bitset = (unsigned int*)(ws + off); off += (size_t)B_N * (A_N / 32) * 4;
  int* n_pos  = (int*)(ws + off);   off += 64;
  float* lossc = (float*)(ws + off); off += (size_t)B_N * A_N * 4;
  float* partial = (float*)(ws + off); off += (size_t)B_N * (A_N / 256) * 4;

  hipMemsetAsync(ws, 0, 64, stream);
  hipLaunchKernelGGL(prep_kernel, dim3(A_N / 256, B_N), dim3(256), 0, stream,
                     loc, priors, dec, pf, flags);
  hipLaunchKernelGGL(sel_kernel, dim3(B_N * O_N * 2), dim3(256), 0, stream,
                     dec, pf, targets, flags, vals, idxs);
  hipLaunchKernelGGL(scan_kernel, dim3(B_N), dim3(64), 0, stream,
                     vals, idxs, p_idx, p_val, bitset, n_pos);
  hipLaunchKernelGGL(anchor_kernel, dim3(A_N / 256, B_N), dim3(256), 0, stream,
                     conf, flags, bitset, lossc, partial);
  hipLaunchKernelGGL(mine_kernel, dim3(B_N), dim3(512), 0, stream,
                     lossc, n_pos, accum);
  hipLaunchKernelGGL(loss_lm_kernel, dim3(B_N), dim3(512), 0, stream,
                     loc, landm, priors, targets, p_idx, p_val, accum, cnts);
  hipLaunchKernelGGL(final_kernel, dim3(1), dim3(256), 0, stream,
                     accum, cnts, partial, B_N * (A_N / 256), out);
}